// Round 6
// baseline (2867.722 us; speedup 1.0000x reference)
//
#include <hip/hip_runtime.h>
#include <math.h>

#define DEV __device__ __forceinline__

#define NN 10000
#define NE 160000
#define DH 64
#define SC 31
#define VC 54
#define TC 50
#define NIR 135
#define FEAT 60

DEV float rcpf(float x) { return __builtin_amdgcn_rcpf(x); }

DEV float geluf(float x) {
    float u = 0.7978845608028654f * (x + 0.044715f * x * x * x);
    u = fminf(fmaxf(u, -9.f), 9.f);
    float e = __expf(2.f * u);
    float th = (e - 1.f) * rcpf(e + 1.f);
    return 0.5f * x * (1.f + th);
}
DEV float sigmoidf_(float x) { return rcpf(1.f + __expf(-x)); }

// ================= CSR build (once per launch) =================
__global__ __launch_bounds__(256) void csr_hist(const int* __restrict__ rcv,
                                                int* __restrict__ counts,
                                                int* __restrict__ rank) {
    int e = blockIdx.x * 256 + threadIdx.x;
    if (e >= NE) return;
    rank[e] = atomicAdd(&counts[rcv[e]], 1);
}

__global__ __launch_bounds__(1024) void csr_scan(const int* __restrict__ counts,
                                                 int* __restrict__ offs) {
    __shared__ int buf[1024];
    __shared__ int carry_s;
    if (threadIdx.x == 0) carry_s = 0;
    __syncthreads();
    for (int base = 0; base < 10240; base += 1024) {
        int i = base + threadIdx.x;
        int v = (i < NN) ? counts[i] : 0;
        buf[threadIdx.x] = v;
        __syncthreads();
        for (int off = 1; off < 1024; off <<= 1) {
            int t = (threadIdx.x >= off) ? buf[threadIdx.x - off] : 0;
            __syncthreads();
            buf[threadIdx.x] += t;
            __syncthreads();
        }
        int cbase = carry_s;
        int incl = buf[threadIdx.x];
        if (i < NN) offs[i] = cbase + incl - v;
        int total = buf[1023];
        __syncthreads();
        if (threadIdx.x == 0) carry_s = cbase + total;
        __syncthreads();
    }
    if (threadIdx.x == 0) offs[NN] = carry_s;
}

__global__ __launch_bounds__(256) void csr_fill(const int* __restrict__ rcv,
                                                const int* __restrict__ offs,
                                                const int* __restrict__ rank,
                                                int* __restrict__ elist) {
    int e = blockIdx.x * 256 + threadIdx.x;
    if (e >= NE) return;
    elist[offs[rcv[e]] + rank[e]] = e;
}

// ================= W3 transpose (once per launch) =================
__global__ __launch_bounds__(256) void w3t_kernel(const float* __restrict__ Wr3,
                                                  float* __restrict__ W3t) {
    int t = blockIdx.x * 256 + threadIdx.x;  // 3*135*64 = 25920
    if (t >= 3 * NIR * DH) return;
    int k = t / (NIR * DH), r = t % (NIR * DH);
    int i = r / DH, j = r % DH;
    W3t[t] = Wr3[k * DH * NIR + j * NIR + i];
}

// ================= r01: R4 -> h1 -> h2 (layers 0,1) =================
__global__ __launch_bounds__(256, 4) void r01_kernel(
    const float* __restrict__ cur, const int* __restrict__ snd, const int* __restrict__ rcv,
    const float* __restrict__ W0, const float* __restrict__ W1,
    float* __restrict__ h2out, int e0, int e1, int ce)
{
    int e = e0 + blockIdx.x * 256 + threadIdx.x;
    if (e >= e1) return;
    int is = snd[e], ir = rcv[e];
    float4 qs = ((const float4*)(cur + (size_t)is * FEAT))[4];
    float4 qr = ((const float4*)(cur + (size_t)ir * FEAT))[4];
    float rx = qs.x - qr.x, ry = qs.y - qr.y, rz = qs.z - qr.z;
    float d = sqrtf(rx * rx + ry * ry + rz * rz);
    float ds = fmaxf(d, 1e-9f);
    float rinv = 1.f / ds;
    float R4[4];
#pragma unroll
    for (int b = 0; b < 4; b++)
        R4[b] = sinf((float)(b + 1) * 1.5707963267948966f * ds) * rinv;

    float h1[DH];
#pragma unroll
    for (int o = 0; o < DH; o++)
        h1[o] = geluf((R4[0] * W0[o] + R4[1] * W0[DH + o] +
                      R4[2] * W0[2 * DH + o] + R4[3] * W0[3 * DH + o]) * 0.5f);

    int eo = e - e0;
#pragma unroll
    for (int c4 = 0; c4 < 4; c4++) {
        float acc[16];
#pragma unroll
        for (int o = 0; o < 16; o++) acc[o] = h1[0] * W1[c4 * 16 + o];
#pragma unroll
        for (int j = 1; j < DH; j++)
#pragma unroll
            for (int o = 0; o < 16; o++) acc[o] += h1[j] * W1[j * DH + c4 * 16 + o];
#pragma unroll
        for (int o = 0; o < 16; o++)
            h2out[(size_t)(c4 * 16 + o) * ce + eo] = geluf(acc[o] * 0.125f);
    }
}

// ================= r23: h2 -> h3 -> 135 radial weights (layers 2,3) =================
__global__ __launch_bounds__(256, 3) void r23_kernel(
    const float* __restrict__ W2, const float* __restrict__ W3t,
    const float* __restrict__ h2buf, float* __restrict__ wout, int ne, int ce)
{
    int eo = blockIdx.x * 256 + threadIdx.x;
    if (eo >= ne) return;
    float h2[DH];
#pragma unroll
    for (int j = 0; j < DH; j++) h2[j] = h2buf[(size_t)j * ce + eo];

    float h3[DH];
#pragma unroll
    for (int c4 = 0; c4 < 4; c4++) {
#pragma unroll
        for (int o = 0; o < 16; o++) h3[c4 * 16 + o] = h2[0] * W2[c4 * 16 + o];
#pragma unroll
        for (int j = 1; j < DH; j++)
#pragma unroll
            for (int o = 0; o < 16; o++) h3[c4 * 16 + o] += h2[j] * W2[j * DH + c4 * 16 + o];
    }
#pragma unroll
    for (int o = 0; o < DH; o++) h3[o] = geluf(h3[o] * 0.125f);

    for (int i = 0; i < NIR; i++) {
        const float* col = W3t + (size_t)i * DH;
        float s0 = 0.f, s1 = 0.f;
#pragma unroll
        for (int j = 0; j < DH; j += 2) {
            s0 += h3[j] * col[j];
            s1 += h3[j + 1] * col[j + 1];
        }
        wout[(size_t)i * ce + eo] = (s0 + s1) * 0.125f;
    }
}

// ================= tp: output-phased TP + projection -> msg =================
#define RC2 0.7071067811865476f
#define RC6 0.40824829046386302f

__global__ __launch_bounds__(256, 3) void tp_kernel(
    const float* __restrict__ cur, const int* __restrict__ snd, const int* __restrict__ rcv,
    const float* __restrict__ Wls, const float* __restrict__ Wlv, const float* __restrict__ Wlt,
    const float* __restrict__ Wms, const float* __restrict__ Wmv, const float* __restrict__ Wmt,
    const float* __restrict__ wp, float* __restrict__ msg, int e0, int e1, int ce)
{
    int e = e0 + blockIdx.x * 256 + threadIdx.x;
    if (e >= e1) return;
    int is = snd[e], ir = rcv[e];
    int eo = e - e0;
    const float* xs = cur + (size_t)is * FEAT;

    // ---- vector features + geometry ----
    float vb[24];
    {
        const float4* p4 = (const float4*)(xs + 16);
#pragma unroll
        for (int i = 0; i < 6; i++) {
            float4 q = p4[i];
            vb[4 * i] = q.x; vb[4 * i + 1] = q.y; vb[4 * i + 2] = q.z; vb[4 * i + 3] = q.w;
        }
    }
    float4 qr = ((const float4*)(cur + (size_t)ir * FEAT))[4];
    float rx = vb[0] - qr.x, ry = vb[1] - qr.y, rz = vb[2] - qr.z;
    float d = sqrtf(rx * rx + ry * ry + rz * rz);
    float dsafe = fmaxf(d, 1e-9f);
    float rinv = 1.f / dsafe;
    float nx = rx * rinv, ny = ry * rinv, nz = rz * rinv;
    float a1[3] = {1.7320508075688772f * nx, 1.7320508075688772f * ny, 1.7320508075688772f * nz};
    float a2[5] = {3.872983346207417f * nx * ny,
                   3.872983346207417f * ny * nz,
                   1.118033988749895f * (3.f * nz * nz - 1.f),
                   3.872983346207417f * nx * nz,
                   1.9364916731037085f * (nx * nx - ny * ny)};
    float A00 = -RC6 * a2[2] + RC2 * a2[4];
    float A01 = RC2 * a2[0];
    float A02 = RC2 * a2[3];
    float A11 = -RC6 * a2[2] - RC2 * a2[4];
    float A12 = RC2 * a2[1];
    float A22 = 2.f * RC6 * a2[2];

    // mv rows 0..7 (projected), row 8 = a1
    float mv[27];
#pragma unroll
    for (int o = 0; o < 24; o++) mv[o] = 0.f;
#pragma unroll
    for (int i = 0; i < 8; i++)
#pragma unroll
        for (int o = 0; o < 8; o++) {
            float w = Wlv[i * 8 + o];
            mv[o * 3 + 0] += vb[i * 3 + 0] * w;
            mv[o * 3 + 1] += vb[i * 3 + 1] * w;
            mv[o * 3 + 2] += vb[i * 3 + 2] * w;
        }
#pragma unroll
    for (int o = 0; o < 24; o++) mv[o] *= 0.3535533905932738f;
    mv[24] = a1[0]; mv[25] = a1[1]; mv[26] = a1[2];

    // ---- scalar features -> ms rows 0..15 (row 16 is constant 1) ----
    float ms[16];
    {
        float sb[16];
        const float4* p4 = (const float4*)xs;
#pragma unroll
        for (int i = 0; i < 4; i++) {
            float4 q = p4[i];
            sb[4 * i] = q.x; sb[4 * i + 1] = q.y; sb[4 * i + 2] = q.z; sb[4 * i + 3] = q.w;
        }
#pragma unroll
        for (int o = 0; o < 16; o++) ms[o] = 0.f;
#pragma unroll
        for (int i = 0; i < 16; i++) {
            float si = sb[i];
#pragma unroll
            for (int o = 0; o < 16; o++) ms[o] += si * Wls[i * 16 + o];
        }
#pragma unroll
        for (int o = 0; o < 16; o++) ms[o] *= 0.25f;
    }

    // ---- tensor features -> mt rows 0..3 (row 4 = a2) ----
    float mt[25];
    {
        float tb[20];
        const float4* p4 = (const float4*)(xs + 40);
#pragma unroll
        for (int i = 0; i < 5; i++) {
            float4 q = p4[i];
            tb[4 * i] = q.x; tb[4 * i + 1] = q.y; tb[4 * i + 2] = q.z; tb[4 * i + 3] = q.w;
        }
#pragma unroll
        for (int o = 0; o < 20; o++) mt[o] = 0.f;
#pragma unroll
        for (int i = 0; i < 4; i++)
#pragma unroll
            for (int o = 0; o < 4; o++) {
                float w = Wlt[i * 4 + o];
#pragma unroll
                for (int c = 0; c < 5; c++) mt[o * 5 + c] += tb[i * 5 + c] * w;
            }
#pragma unroll
        for (int o = 0; o < 20; o++) mt[o] *= 0.5f;
#pragma unroll
        for (int c = 0; c < 5; c++) mt[20 + c] = a2[c];
    }

#define WD(i) (wp[(size_t)(i) * ce + eo])
    float4* mrow = (float4*)(msg + (size_t)e * 72);
    const float kS = 0.17960530202677491f;  // 1/sqrt(31)
    const float kV = 0.13608276348795434f;  // 1/sqrt(54)
    const float kT = 0.1414213562373095f;   // 1/sqrt(50)

    // ================= Pass S: aS[28] =================
    {
        float aS[28];
#pragma unroll
        for (int o = 0; o < 28; o++) aS[o] = 0.f;
        // ms rows 0..16
#pragma unroll
        for (int i = 0; i < 17; i++) {
            float mi = (i < 16) ? ms[i] : 1.f;
            float sm = mi * WD(i);
#pragma unroll
            for (int o = 0; o < 28; o++) aS[o] += sm * Wms[i * 28 + o];
        }
        // mv rows: dot(v, a1)
#pragma unroll
        for (int mm = 0; mm < 9; mm++) {
            float sval = mv[mm * 3] * a1[0] + mv[mm * 3 + 1] * a1[1] + mv[mm * 3 + 2] * a1[2];
            float sm = sval * WD(17 + mm);
#pragma unroll
            for (int o = 0; o < 28; o++) aS[o] += sm * Wms[(17 + mm) * 28 + o];
        }
        // mt rows: trace(T·A) (both symmetric)
#pragma unroll
        for (int mm = 0; mm < 5; mm++) {
            float t0 = mt[mm * 5], t1 = mt[mm * 5 + 1], t2 = mt[mm * 5 + 2], t3 = mt[mm * 5 + 3], t4 = mt[mm * 5 + 4];
            float T00 = -RC6 * t2 + RC2 * t4, T01 = RC2 * t0, T02 = RC2 * t3;
            float T11 = -RC6 * t2 - RC2 * t4, T12 = RC2 * t1, T22 = 2.f * RC6 * t2;
            float tr = T00 * A00 + T11 * A11 + T22 * A22 + 2.f * (T01 * A01 + T02 * A02 + T12 * A12);
            float sm = tr * WD(26 + mm);
#pragma unroll
            for (int o = 0; o < 28; o++) aS[o] += sm * Wms[(26 + mm) * 28 + o];
        }
#pragma unroll
        for (int i = 0; i < 7; i++) {
            float4 q;
            q.x = aS[4 * i] * kS; q.y = aS[4 * i + 1] * kS;
            q.z = aS[4 * i + 2] * kS; q.w = aS[4 * i + 3] * kS;
            mrow[i] = q;
        }
    }

    // ================= Pass V: aV[24] =================
    {
        float aV[24];
#pragma unroll
        for (int o = 0; o < 24; o++) aV[o] = 0.f;
        // helper lambda-free macro: add vec*(wm) against Wmv row
#define ADDV(vx, vy, vz, wm, row)                                           \
        {                                                                   \
            float _x = (vx) * (wm), _y = (vy) * (wm), _z = (vz) * (wm);     \
            _Pragma("unroll")                                               \
            for (int o = 0; o < 8; o++) {                                   \
                float w = Wmv[(row) * 8 + o];                               \
                aV[o * 3] += _x * w; aV[o * 3 + 1] += _y * w; aV[o * 3 + 2] += _z * w; \
            }                                                               \
        }
        // ms rows: mi * a1
#pragma unroll
        for (int i = 0; i < 17; i++) {
            float mi = (i < 16) ? ms[i] : 1.f;
            ADDV(mi * a1[0], mi * a1[1], mi * a1[2], WD(SC + i), i);
        }
        // mv rows
#pragma unroll
        for (int mm = 0; mm < 9; mm++) {
            float v0 = mv[mm * 3], v1 = mv[mm * 3 + 1], v2 = mv[mm * 3 + 2];
            ADDV(v0, v1, v2, WD(SC + 17 + mm), 17 + mm);
            ADDV(v1 * a1[2] - v2 * a1[1], v2 * a1[0] - v0 * a1[2], v0 * a1[1] - v1 * a1[0],
                 WD(SC + 26 + mm), 26 + mm);
            ADDV(A00 * v0 + A01 * v1 + A02 * v2, A01 * v0 + A11 * v1 + A12 * v2,
                 A02 * v0 + A12 * v1 + A22 * v2, WD(SC + 35 + mm), 35 + mm);
        }
        // mt rows
#pragma unroll
        for (int mm = 0; mm < 5; mm++) {
            float t0 = mt[mm * 5], t1 = mt[mm * 5 + 1], t2 = mt[mm * 5 + 2], t3 = mt[mm * 5 + 3], t4 = mt[mm * 5 + 4];
            float T00 = -RC6 * t2 + RC2 * t4, T01 = RC2 * t0, T02 = RC2 * t3;
            float T11 = -RC6 * t2 - RC2 * t4, T12 = RC2 * t1, T22 = 2.f * RC6 * t2;
            ADDV(T00 * a1[0] + T01 * a1[1] + T02 * a1[2],
                 T01 * a1[0] + T11 * a1[1] + T12 * a1[2],
                 T02 * a1[0] + T12 * a1[1] + T22 * a1[2], WD(SC + 44 + mm), 44 + mm);
            float P01 = T00 * A01 + T01 * A11 + T02 * A12;
            float P02 = T00 * A02 + T01 * A12 + T02 * A22;
            float P10 = T01 * A00 + T11 * A01 + T12 * A02;
            float P12 = T01 * A02 + T11 * A12 + T12 * A22;
            float P20 = T02 * A00 + T12 * A01 + T22 * A02;
            float P21 = T02 * A01 + T12 * A11 + T22 * A12;
            ADDV(P12 - P21, P20 - P02, P01 - P10, WD(SC + 49 + mm), 49 + mm);
        }
#undef ADDV
#pragma unroll
        for (int i = 0; i < 6; i++) {
            float4 q;
            q.x = aV[4 * i] * kV; q.y = aV[4 * i + 1] * kV;
            q.z = aV[4 * i + 2] * kV; q.w = aV[4 * i + 3] * kV;
            mrow[7 + i] = q;
        }
    }

    // ================= Pass T: aT[20] =================
    {
        float aT[20];
#pragma unroll
        for (int o = 0; o < 20; o++) aT[o] = 0.f;
#define ADDT(u0, u1, u2, u3, u4, wm, row)                                   \
        {                                                                   \
            float _0 = (u0) * (wm), _1 = (u1) * (wm), _2 = (u2) * (wm),     \
                  _3 = (u3) * (wm), _4 = (u4) * (wm);                       \
            _Pragma("unroll")                                               \
            for (int o = 0; o < 4; o++) {                                   \
                float w = Wmt[(row) * 4 + o];                               \
                aT[o * 5] += _0 * w; aT[o * 5 + 1] += _1 * w;               \
                aT[o * 5 + 2] += _2 * w; aT[o * 5 + 3] += _3 * w;           \
                aT[o * 5 + 4] += _4 * w;                                    \
            }                                                               \
        }
#define TO5T(M00, M01, M02, M10, M11, M12, M20, M21, M22, wm, row)          \
        ADDT(RC2 * ((M01) + (M10)), RC2 * ((M12) + (M21)),                  \
             RC6 * (-(M00) - (M11) + 2.f * (M22)),                         \
             RC2 * ((M02) + (M20)), RC2 * ((M00) - (M11)), wm, row)
        // ms rows: mi * a2
#pragma unroll
        for (int i = 0; i < 17; i++) {
            float mi = (i < 16) ? ms[i] : 1.f;
            ADDT(mi * a2[0], mi * a2[1], mi * a2[2], mi * a2[3], mi * a2[4],
                 WD(SC + VC + i), i);
        }
        // mv rows
#pragma unroll
        for (int mm = 0; mm < 9; mm++) {
            float v0 = mv[mm * 3], v1 = mv[mm * 3 + 1], v2 = mv[mm * 3 + 2];
            TO5T(v0 * a1[0], v0 * a1[1], v0 * a1[2],
                 v1 * a1[0], v1 * a1[1], v1 * a1[2],
                 v2 * a1[0], v2 * a1[1], v2 * a1[2],
                 WD(SC + VC + 17 + mm), 17 + mm);
            float C200 = v1 * A02 - v2 * A01, C210 = v2 * A00 - v0 * A02, C220 = v0 * A01 - v1 * A00;
            float C201 = v1 * A12 - v2 * A11, C211 = v2 * A01 - v0 * A12, C221 = v0 * A11 - v1 * A01;
            float C202 = v1 * A22 - v2 * A12, C212 = v2 * A02 - v0 * A22, C222 = v0 * A12 - v1 * A02;
            TO5T(C200, C201, C202, C210, C211, C212, C220, C221, C222,
                 WD(SC + VC + 26 + mm), 26 + mm);
        }
        // mt rows
#pragma unroll
        for (int mm = 0; mm < 5; mm++) {
            float t0 = mt[mm * 5], t1 = mt[mm * 5 + 1], t2 = mt[mm * 5 + 2], t3 = mt[mm * 5 + 3], t4 = mt[mm * 5 + 4];
            ADDT(t0, t1, t2, t3, t4, WD(SC + VC + 35 + mm), 35 + mm);
            float T00 = -RC6 * t2 + RC2 * t4, T01 = RC2 * t0, T02 = RC2 * t3;
            float T11 = -RC6 * t2 - RC2 * t4, T12 = RC2 * t1, T22 = 2.f * RC6 * t2;
            float u0 = a1[0], u1 = a1[1], u2 = a1[2];
            float C300 = u1 * T02 - u2 * T01, C310 = u2 * T00 - u0 * T02, C320 = u0 * T01 - u1 * T00;
            float C301 = u1 * T12 - u2 * T11, C311 = u2 * T01 - u0 * T12, C321 = u0 * T11 - u1 * T01;
            float C302 = u1 * T22 - u2 * T12, C312 = u2 * T02 - u0 * T22, C322 = u0 * T12 - u1 * T02;
            TO5T(C300, C301, C302, C310, C311, C312, C320, C321, C322,
                 WD(SC + VC + 40 + mm), 40 + mm);
            float P00 = T00 * A00 + T01 * A01 + T02 * A02;
            float P01 = T00 * A01 + T01 * A11 + T02 * A12;
            float P02 = T00 * A02 + T01 * A12 + T02 * A22;
            float P10 = T01 * A00 + T11 * A01 + T12 * A02;
            float P11 = T01 * A01 + T11 * A11 + T12 * A12;
            float P12 = T01 * A02 + T11 * A12 + T12 * A22;
            float P20 = T02 * A00 + T12 * A01 + T22 * A02;
            float P21 = T02 * A01 + T12 * A11 + T22 * A12;
            float P22 = T02 * A02 + T12 * A12 + T22 * A22;
            TO5T(P00, P01, P02, P10, P11, P12, P20, P21, P22,
                 WD(SC + VC + 45 + mm), 45 + mm);
        }
#undef TO5T
#undef ADDT
#pragma unroll
        for (int i = 0; i < 5; i++) {
            float4 q;
            q.x = aT[4 * i] * kT; q.y = aT[4 * i + 1] * kT;
            q.z = aT[4 * i + 2] * kT; q.w = aT[4 * i + 3] * kT;
            mrow[13 + i] = q;
        }
    }
#undef WD
}

// ================= gather: per-node edge-list sum (2-way pipelined) =================
__global__ __launch_bounds__(256, 8) void gather_kernel(
    const float4* __restrict__ msg4, const int* __restrict__ offs,
    const int* __restrict__ elist, float4* __restrict__ agg4)
{
    int t = blockIdx.x * 256 + threadIdx.x;
    if (t >= NN * 18) return;
    int n = t / 18;
    int q = t - n * 18;
    int beg = offs[n], end = offs[n + 1];
    float4 acc0 = {0.f, 0.f, 0.f, 0.f};
    float4 acc1 = {0.f, 0.f, 0.f, 0.f};
    int j = beg;
    for (; j + 1 < end; j += 2) {
        int ea = elist[j], eb = elist[j + 1];
        float4 ma = msg4[(size_t)ea * 18 + q];
        float4 mb = msg4[(size_t)eb * 18 + q];
        acc0.x += ma.x; acc0.y += ma.y; acc0.z += ma.z; acc0.w += ma.w;
        acc1.x += mb.x; acc1.y += mb.y; acc1.z += mb.z; acc1.w += mb.w;
    }
    if (j < end) {
        float4 ma = msg4[(size_t)elist[j] * 18 + q];
        acc0.x += ma.x; acc0.y += ma.y; acc0.z += ma.z; acc0.w += ma.w;
    }
    float4 r;
    r.x = acc0.x + acc1.x; r.y = acc0.y + acc1.y;
    r.z = acc0.z + acc1.z; r.w = acc0.w + acc1.w;
    agg4[(size_t)n * 18 + q] = r;
}

// ================= node update =================
__global__ __launch_bounds__(256) void node_kernel(
    const float* __restrict__ cur, const float* __restrict__ agg,
    const float* __restrict__ Wns, const float* __restrict__ Wnv, const float* __restrict__ Wnt,
    const float* __restrict__ Wps, const float* __restrict__ Wpv, const float* __restrict__ Wpt,
    float* __restrict__ dst)
{
    int n = blockIdx.x * 256 + threadIdx.x;
    if (n >= NN) return;
    const float* xn = cur + (size_t)n * FEAT;
    const float* ag = agg + (size_t)n * 72;
    const float invE = 0.0025f;  // 1/sqrt(160000)

    float msv[28];
#pragma unroll
    for (int o = 0; o < 28; o++) msv[o] = ag[o] * invE;
#pragma unroll
    for (int i = 0; i < 16; i++) {
        float si = xn[i] * 0.25f;
#pragma unroll
        for (int o = 0; o < 28; o++) msv[o] += si * Wns[i * 28 + o];
    }
    float mvv[8][3];
#pragma unroll
    for (int o = 0; o < 8; o++)
#pragma unroll
        for (int c = 0; c < 3; c++) mvv[o][c] = ag[28 + o * 3 + c] * invE;
#pragma unroll
    for (int i = 0; i < 8; i++)
#pragma unroll
        for (int o = 0; o < 8; o++) {
            float w = Wnv[i * 8 + o] * 0.3535533905932738f;
#pragma unroll
            for (int c = 0; c < 3; c++) mvv[o][c] += xn[16 + i * 3 + c] * w;
        }
    float mtv[4][5];
#pragma unroll
    for (int o = 0; o < 4; o++)
#pragma unroll
        for (int c = 0; c < 5; c++) mtv[o][c] = ag[52 + o * 5 + c] * invE;
#pragma unroll
    for (int i = 0; i < 4; i++)
#pragma unroll
        for (int o = 0; o < 4; o++) {
            float w = Wnt[i * 4 + o] * 0.5f;
#pragma unroll
            for (int c = 0; c < 5; c++) mtv[o][c] += xn[40 + i * 5 + c] * w;
        }

    float g[12];
#pragma unroll
    for (int j = 0; j < 12; j++) g[j] = sigmoidf_(msv[16 + j]);
    float hs[16];
#pragma unroll
    for (int i = 0; i < 16; i++) hs[i] = geluf(msv[i]);

    float outv[60];
#pragma unroll
    for (int o = 0; o < 16; o++) outv[o] = 0.f;
#pragma unroll
    for (int i = 0; i < 16; i++) {
        float si = hs[i] * 0.25f;
#pragma unroll
        for (int o = 0; o < 16; o++) outv[o] += si * Wps[i * 16 + o];
    }
#pragma unroll
    for (int o = 0; o < 8; o++)
#pragma unroll
        for (int c = 0; c < 3; c++) outv[16 + o * 3 + c] = 0.f;
#pragma unroll
    for (int i = 0; i < 8; i++) {
        float gi = g[i];
#pragma unroll
        for (int o = 0; o < 8; o++) {
            float w = Wpv[i * 8 + o] * 0.3535533905932738f * gi;
#pragma unroll
            for (int c = 0; c < 3; c++) outv[16 + o * 3 + c] += mvv[i][c] * w;
        }
    }
#pragma unroll
    for (int o = 0; o < 4; o++)
#pragma unroll
        for (int c = 0; c < 5; c++) outv[40 + o * 5 + c] = 0.f;
#pragma unroll
    for (int i = 0; i < 4; i++) {
        float gi = g[8 + i];
#pragma unroll
        for (int o = 0; o < 4; o++) {
            float w = Wpt[i * 4 + o] * 0.5f * gi;
#pragma unroll
            for (int c = 0; c < 5; c++) outv[40 + o * 5 + c] += mtv[i][c] * w;
        }
    }

    float4* dst4 = (float4*)(dst + (size_t)n * FEAT);
#pragma unroll
    for (int i = 0; i < 15; i++) {
        float4 q;
        q.x = outv[4 * i]; q.y = outv[4 * i + 1]; q.z = outv[4 * i + 2]; q.w = outv[4 * i + 3];
        dst4[i] = q;
    }
}

// ================= host =================
extern "C" void kernel_launch(void* const* d_in, const int* in_sizes, int n_in,
                              void* d_out, int out_size, void* d_ws, size_t ws_size,
                              hipStream_t stream)
{
    const float* x    = (const float*)d_in[0];
    const float* Wl_s = (const float*)d_in[1];
    const float* Wl_v = (const float*)d_in[2];
    const float* Wl_t = (const float*)d_in[3];
    const float* Wr0  = (const float*)d_in[4];
    const float* Wr1  = (const float*)d_in[5];
    const float* Wr2  = (const float*)d_in[6];
    const float* Wr3  = (const float*)d_in[7];
    const float* Wm_s = (const float*)d_in[8];
    const float* Wm_v = (const float*)d_in[9];
    const float* Wm_t = (const float*)d_in[10];
    const float* Wn_s = (const float*)d_in[11];
    const float* Wn_v = (const float*)d_in[12];
    const float* Wn_t = (const float*)d_in[13];
    const float* Wp_s = (const float*)d_in[14];
    const float* Wp_v = (const float*)d_in[15];
    const float* Wp_t = (const float*)d_in[16];
    const int* snd = (const int*)d_in[17];
    const int* rcv = (const int*)d_in[18];
    float* out = (float*)d_out;

    char* ws = (char*)d_ws;
    size_t off = 0;
    float* cur    = (float*)(ws + off); off += (size_t)NN * FEAT * 4;        // 2,400,000
    float* agg    = (float*)(ws + off); off += (size_t)NN * 72 * 4;          // 2,880,000
    float* msg    = (float*)(ws + off); off += (size_t)NE * 72 * 4;          // 46,080,000
    int*   counts = (int*)(ws + off);   off += (size_t)NN * 4;               // 40,000
    int*   offs   = (int*)(ws + off);   off += (size_t)(NN + 1) * 4 + 12;    // 40,016
    int*   rank   = (int*)(ws + off);   off += (size_t)NE * 4;               // 640,000
    int*   elist  = (int*)(ws + off);   off += (size_t)NE * 4;               // 640,000
    float* W3t    = (float*)(ws + off); off += (size_t)3 * NIR * DH * 4;     // 103,680
    // per-chunk buffers: h2 (64*ce) + w (135*ce)
    size_t avail = (ws_size > off) ? (ws_size - off) : 0;
    long long chunkE = (long long)(avail / ((size_t)(DH + NIR) * sizeof(float)));
    chunkE &= ~255LL;
    if (chunkE > NE) chunkE = NE;
    if (chunkE < 4096) chunkE = 4096;
    float* h2buf = (float*)(ws + off);
    float* wbuf  = h2buf + (size_t)DH * chunkE;

    hipMemcpyAsync(cur, x, (size_t)NN * FEAT * 4, hipMemcpyDeviceToDevice, stream);
    hipMemsetAsync(counts, 0, (size_t)NN * 4, stream);
    csr_hist<<<(NE + 255) / 256, 256, 0, stream>>>(rcv, counts, rank);
    csr_scan<<<1, 1024, 0, stream>>>(counts, offs);
    csr_fill<<<(NE + 255) / 256, 256, 0, stream>>>(rcv, offs, rank, elist);
    w3t_kernel<<<(3 * NIR * DH + 255) / 256, 256, 0, stream>>>(Wr3, W3t);

    for (int k = 0; k < 3; k++) {
        const float* W0  = Wr0 + (size_t)k * 4 * DH;
        const float* W1  = Wr1 + (size_t)k * DH * DH;
        const float* W2  = Wr2 + (size_t)k * DH * DH;
        const float* W3tk= W3t + (size_t)k * NIR * DH;
        const float* Wls = Wl_s + (size_t)k * 16 * 16;
        const float* Wlv = Wl_v + (size_t)k * 8 * 8;
        const float* Wlt = Wl_t + (size_t)k * 4 * 4;
        const float* Wms = Wm_s + (size_t)k * SC * 28;
        const float* Wmv = Wm_v + (size_t)k * VC * 8;
        const float* Wmt = Wm_t + (size_t)k * TC * 4;
        const float* Wns = Wn_s + (size_t)k * 16 * 28;
        const float* Wnv = Wn_v + (size_t)k * 8 * 8;
        const float* Wnt = Wn_t + (size_t)k * 4 * 4;
        const float* Wps = Wp_s + (size_t)k * 16 * 16;
        const float* Wpv = Wp_v + (size_t)k * 8 * 8;
        const float* Wpt = Wp_t + (size_t)k * 4 * 4;

        for (long long e0 = 0; e0 < NE; e0 += chunkE) {
            long long e1 = e0 + chunkE; if (e1 > NE) e1 = NE;
            long long n = e1 - e0;
            int nb = (int)((n + 255) / 256);
            r01_kernel<<<nb, 256, 0, stream>>>(cur, snd, rcv, W0, W1,
                                               h2buf, (int)e0, (int)e1, (int)chunkE);
            r23_kernel<<<nb, 256, 0, stream>>>(W2, W3tk, h2buf, wbuf, (int)n, (int)chunkE);
            tp_kernel<<<nb, 256, 0, stream>>>(cur, snd, rcv, Wls, Wlv, Wlt,
                                              Wms, Wmv, Wmt, wbuf, msg,
                                              (int)e0, (int)e1, (int)chunkE);
        }
        gather_kernel<<<(NN * 18 + 255) / 256, 256, 0, stream>>>(
            (const float4*)msg, offs, elist, (float4*)agg);
        float* dst = (k == 2) ? out : cur;
        node_kernel<<<(NN + 255) / 256, 256, 0, stream>>>(cur, agg, Wns, Wnv, Wnt,
                                                          Wps, Wpv, Wpt, dst);
    }
}

// Round 7
// 1401.335 us; speedup vs baseline: 2.0464x; 2.0464x over previous
//
#include <hip/hip_runtime.h>
#include <math.h>

#define DEV __device__ __forceinline__

#define NN 10000
#define NE 160000
#define DH 64
#define SC 31
#define VC 54
#define TC 50
#define NIR 135
#define FEAT 60
#define MSTRIDE 80   // padded msg row (floats): 320B, 64B-aligned

DEV float rcpf(float x) { return __builtin_amdgcn_rcpf(x); }

DEV float geluf(float x) {
    float u = 0.7978845608028654f * (x + 0.044715f * x * x * x);
    u = fminf(fmaxf(u, -9.f), 9.f);
    float e = __expf(2.f * u);
    float th = (e - 1.f) * rcpf(e + 1.f);
    return 0.5f * x * (1.f + th);
}
DEV float sigmoidf_(float x) { return rcpf(1.f + __expf(-x)); }

// ================= CSR build (once per launch) =================
__global__ __launch_bounds__(256) void csr_hist(const int* __restrict__ rcv,
                                                int* __restrict__ counts,
                                                int* __restrict__ rank) {
    int e = blockIdx.x * 256 + threadIdx.x;
    if (e >= NE) return;
    rank[e] = atomicAdd(&counts[rcv[e]], 1);
}

__global__ __launch_bounds__(1024) void csr_scan(const int* __restrict__ counts,
                                                 int* __restrict__ offs) {
    __shared__ int buf[1024];
    __shared__ int carry_s;
    if (threadIdx.x == 0) carry_s = 0;
    __syncthreads();
    for (int base = 0; base < 10240; base += 1024) {
        int i = base + threadIdx.x;
        int v = (i < NN) ? counts[i] : 0;
        buf[threadIdx.x] = v;
        __syncthreads();
        for (int off = 1; off < 1024; off <<= 1) {
            int t = (threadIdx.x >= off) ? buf[threadIdx.x - off] : 0;
            __syncthreads();
            buf[threadIdx.x] += t;
            __syncthreads();
        }
        int cbase = carry_s;
        int incl = buf[threadIdx.x];
        if (i < NN) offs[i] = cbase + incl - v;
        int total = buf[1023];
        __syncthreads();
        if (threadIdx.x == 0) carry_s = cbase + total;
        __syncthreads();
    }
    if (threadIdx.x == 0) offs[NN] = carry_s;
}

__global__ __launch_bounds__(256) void csr_fill(const int* __restrict__ rcv,
                                                const int* __restrict__ offs,
                                                const int* __restrict__ rank,
                                                int* __restrict__ elist) {
    int e = blockIdx.x * 256 + threadIdx.x;
    if (e >= NE) return;
    elist[offs[rcv[e]] + rank[e]] = e;
}

// ================= W3 transpose (once per launch) =================
__global__ __launch_bounds__(256) void w3t_kernel(const float* __restrict__ Wr3,
                                                  float* __restrict__ W3t) {
    int t = blockIdx.x * 256 + threadIdx.x;  // 3*135*64 = 25920
    if (t >= 3 * NIR * DH) return;
    int k = t / (NIR * DH), r = t % (NIR * DH);
    int i = r / DH, j = r % DH;
    W3t[t] = Wr3[k * DH * NIR + j * NIR + i];
}

// ================= r01: R4 -> h1 -> h2 (layers 0,1) =================
__global__ __launch_bounds__(256) void r01_kernel(
    const float* __restrict__ cur, const int* __restrict__ snd, const int* __restrict__ rcv,
    const float* __restrict__ W0, const float* __restrict__ W1,
    float* __restrict__ h2out, int e0, int e1, int ce)
{
    int e = e0 + blockIdx.x * 256 + threadIdx.x;
    if (e >= e1) return;
    int is = snd[e], ir = rcv[e];
    float4 qs = ((const float4*)(cur + (size_t)is * FEAT))[4];
    float4 qr = ((const float4*)(cur + (size_t)ir * FEAT))[4];
    float rx = qs.x - qr.x, ry = qs.y - qr.y, rz = qs.z - qr.z;
    float d = sqrtf(rx * rx + ry * ry + rz * rz);
    float ds = fmaxf(d, 1e-9f);
    float rinv = 1.f / ds;
    float R4[4];
#pragma unroll
    for (int b = 0; b < 4; b++)
        R4[b] = sinf((float)(b + 1) * 1.5707963267948966f * ds) * rinv;

    float h1[DH];
#pragma unroll
    for (int o = 0; o < DH; o++)
        h1[o] = geluf((R4[0] * W0[o] + R4[1] * W0[DH + o] +
                      R4[2] * W0[2 * DH + o] + R4[3] * W0[3 * DH + o]) * 0.5f);

    int eo = e - e0;
#pragma unroll
    for (int c4 = 0; c4 < 4; c4++) {
        float acc[16];
#pragma unroll
        for (int o = 0; o < 16; o++) acc[o] = h1[0] * W1[c4 * 16 + o];
#pragma unroll
        for (int j = 1; j < DH; j++)
#pragma unroll
            for (int o = 0; o < 16; o++) acc[o] += h1[j] * W1[j * DH + c4 * 16 + o];
#pragma unroll
        for (int o = 0; o < 16; o++)
            h2out[(size_t)(c4 * 16 + o) * ce + eo] = geluf(acc[o] * 0.125f);
    }
}

// ================= r2: h2 -> h3 (layer 2) =================
__global__ __launch_bounds__(256) void r2_kernel(
    const float* __restrict__ W2, const float* __restrict__ h2buf,
    float* __restrict__ h3out, int ne, int ce)
{
    int eo = blockIdx.x * 256 + threadIdx.x;
    if (eo >= ne) return;
    float h2[DH];
#pragma unroll
    for (int j = 0; j < DH; j++) h2[j] = h2buf[(size_t)j * ce + eo];

#pragma unroll
    for (int c4 = 0; c4 < 4; c4++) {
        float acc[16];
#pragma unroll
        for (int o = 0; o < 16; o++) acc[o] = h2[0] * W2[c4 * 16 + o];
#pragma unroll
        for (int j = 1; j < DH; j++)
#pragma unroll
            for (int o = 0; o < 16; o++) acc[o] += h2[j] * W2[j * DH + c4 * 16 + o];
#pragma unroll
        for (int o = 0; o < 16; o++)
            h3out[(size_t)(c4 * 16 + o) * ce + eo] = geluf(acc[o] * 0.125f);
    }
}

// ================= r3: h3 -> 135 radial weights =================
__global__ __launch_bounds__(256) void r3_kernel(
    const float* __restrict__ W3t, const float* __restrict__ h3buf,
    float* __restrict__ wout, int ne, int ce)
{
    int eo = blockIdx.x * 256 + threadIdx.x;
    if (eo >= ne) return;
    float h3[DH];
#pragma unroll
    for (int j = 0; j < DH; j++) h3[j] = h3buf[(size_t)j * ce + eo];

    for (int i = 0; i < NIR; i++) {
        const float* col = W3t + (size_t)i * DH;
        float s0 = 0.f, s1 = 0.f;
#pragma unroll
        for (int j = 0; j < DH; j += 2) {
            s0 += h3[j] * col[j];
            s1 += h3[j + 1] * col[j + 1];
        }
        wout[(size_t)i * ce + eo] = (s0 + s1) * 0.125f;
    }
}

// ================= tp: TP + projection -> msg (edge order, padded rows) =================
DEV void add_s_row(float sval, float wm, const float* __restrict__ Wms, int mrow, float (&aS)[28]) {
    float sm = sval * wm;
#pragma unroll
    for (int o = 0; o < 28; o++) aS[o] += sm * Wms[mrow * 28 + o];
}
DEV void add_v_row(float vx, float vy, float vz, float wm, const float* __restrict__ Wmv, int mrow, float (&aV)[8][3]) {
    vx *= wm; vy *= wm; vz *= wm;
#pragma unroll
    for (int o = 0; o < 8; o++) {
        float w = Wmv[mrow * 8 + o];
        aV[o][0] += vx * w; aV[o][1] += vy * w; aV[o][2] += vz * w;
    }
}
DEV void add_t_row(float t0, float t1, float t2, float t3, float t4, float wm, const float* __restrict__ Wmt, int mrow, float (&aT)[4][5]) {
    t0 *= wm; t1 *= wm; t2 *= wm; t3 *= wm; t4 *= wm;
#pragma unroll
    for (int o = 0; o < 4; o++) {
        float w = Wmt[mrow * 4 + o];
        aT[o][0] += t0 * w; aT[o][1] += t1 * w; aT[o][2] += t2 * w; aT[o][3] += t3 * w; aT[o][4] += t4 * w;
    }
}
#define RC2 0.7071067811865476f
#define RC6 0.40824829046386302f
DEV void to5_add(float M00, float M01, float M02, float M10, float M11, float M12,
                 float M20, float M21, float M22, float wm, const float* __restrict__ Wmt,
                 int mrow, float (&aT)[4][5]) {
    add_t_row(RC2 * (M01 + M10), RC2 * (M12 + M21), RC6 * (-M00 - M11 + 2.f * M22),
              RC2 * (M02 + M20), RC2 * (M00 - M11), wm, Wmt, mrow, aT);
}

__global__ __launch_bounds__(256) void tp_kernel(
    const float* __restrict__ cur, const int* __restrict__ snd, const int* __restrict__ rcv,
    const float* __restrict__ Wls, const float* __restrict__ Wlv, const float* __restrict__ Wlt,
    const float* __restrict__ Wms, const float* __restrict__ Wmv, const float* __restrict__ Wmt,
    const float* __restrict__ wp, float* __restrict__ msg, int e0, int e1, int ce)
{
    int e = e0 + blockIdx.x * 256 + threadIdx.x;
    if (e >= e1) return;
    int is = snd[e], ir = rcv[e];
    int eo = e - e0;

    // sender features (60 floats, 15x float4)
    float xb[60];
    {
        const float4* xs4 = (const float4*)(cur + (size_t)is * FEAT);
#pragma unroll
        for (int i = 0; i < 15; i++) {
            float4 q = xs4[i];
            xb[4 * i] = q.x; xb[4 * i + 1] = q.y; xb[4 * i + 2] = q.z; xb[4 * i + 3] = q.w;
        }
    }
    float4 qr = ((const float4*)(cur + (size_t)ir * FEAT))[4];
    float rx = xb[16] - qr.x, ry = xb[17] - qr.y, rz = xb[18] - qr.z;
    float d = sqrtf(rx * rx + ry * ry + rz * rz);
    float dsafe = fmaxf(d, 1e-9f);
    float rinv = 1.f / dsafe;
    float nx = rx * rinv, ny = ry * rinv, nz = rz * rinv;
    float a1[3] = {1.7320508075688772f * nx, 1.7320508075688772f * ny, 1.7320508075688772f * nz};
    float a2[5] = {3.872983346207417f * nx * ny,
                   3.872983346207417f * ny * nz,
                   1.118033988749895f * (3.f * nz * nz - 1.f),
                   3.872983346207417f * nx * nz,
                   1.9364916731037085f * (nx * nx - ny * ny)};

    // ms = [s_snd @ Wls /4, 1]
    float ms[17];
#pragma unroll
    for (int o = 0; o < 16; o++) ms[o] = 0.f;
#pragma unroll
    for (int i = 0; i < 16; i++) {
        float si = xb[i];
#pragma unroll
        for (int o = 0; o < 16; o++) ms[o] += si * Wls[i * 16 + o];
    }
#pragma unroll
    for (int o = 0; o < 16; o++) ms[o] *= 0.25f;
    ms[16] = 1.f;

    // mv = [linL(v_snd, Wlv)/sqrt(8), a1]
    float mv[9][3];
#pragma unroll
    for (int o = 0; o < 8; o++) { mv[o][0] = 0.f; mv[o][1] = 0.f; mv[o][2] = 0.f; }
#pragma unroll
    for (int i = 0; i < 8; i++)
#pragma unroll
        for (int o = 0; o < 8; o++) {
            float w = Wlv[i * 8 + o];
            mv[o][0] += xb[16 + i * 3 + 0] * w;
            mv[o][1] += xb[16 + i * 3 + 1] * w;
            mv[o][2] += xb[16 + i * 3 + 2] * w;
        }
#pragma unroll
    for (int o = 0; o < 8; o++) { mv[o][0] *= 0.3535533905932738f; mv[o][1] *= 0.3535533905932738f; mv[o][2] *= 0.3535533905932738f; }
    mv[8][0] = a1[0]; mv[8][1] = a1[1]; mv[8][2] = a1[2];

    // mt = [linL(t_snd, Wlt)/2, a2]
    float mt[5][5];
#pragma unroll
    for (int o = 0; o < 4; o++)
#pragma unroll
        for (int c = 0; c < 5; c++) mt[o][c] = 0.f;
#pragma unroll
    for (int i = 0; i < 4; i++)
#pragma unroll
        for (int o = 0; o < 4; o++) {
            float w = Wlt[i * 4 + o];
#pragma unroll
            for (int c = 0; c < 5; c++) mt[o][c] += xb[40 + i * 5 + c] * w;
        }
#pragma unroll
    for (int o = 0; o < 4; o++)
#pragma unroll
        for (int c = 0; c < 5; c++) mt[o][c] *= 0.5f;
#pragma unroll
    for (int c = 0; c < 5; c++) mt[4][c] = a2[c];

    // A = to_mat(a2), symmetric
    float A00 = -RC6 * a2[2] + RC2 * a2[4];
    float A01 = RC2 * a2[0];
    float A02 = RC2 * a2[3];
    float A11 = -RC6 * a2[2] - RC2 * a2[4];
    float A12 = RC2 * a2[1];
    float A22 = 2.f * RC6 * a2[2];

#define WD(i) (wp[(size_t)(i) * ce + eo])

    float aS[28]; float aV[8][3]; float aT[4][5];
#pragma unroll
    for (int o = 0; o < 28; o++) aS[o] = 0.f;
#pragma unroll
    for (int o = 0; o < 8; o++) { aV[o][0] = 0.f; aV[o][1] = 0.f; aV[o][2] = 0.f; }
#pragma unroll
    for (int o = 0; o < 4; o++)
#pragma unroll
        for (int c = 0; c < 5; c++) aT[o][c] = 0.f;

    // scalar block: rows i = 0..16
#pragma unroll
    for (int i = 0; i < 17; i++) {
        float mi = ms[i];
        add_s_row(mi, WD(i), Wms, i, aS);
        add_v_row(mi * a1[0], mi * a1[1], mi * a1[2], WD(SC + i), Wmv, i, aV);
        add_t_row(mi * a2[0], mi * a2[1], mi * a2[2], mi * a2[3], mi * a2[4],
                  WD(SC + VC + i), Wmt, i, aT);
    }

    // vector block: mm = 0..8
#pragma unroll
    for (int mm = 0; mm < 9; mm++) {
        float v0 = mv[mm][0], v1 = mv[mm][1], v2 = mv[mm][2];
        add_s_row(v0 * a1[0] + v1 * a1[1] + v2 * a1[2], WD(17 + mm), Wms, 17 + mm, aS);
        add_v_row(v0, v1, v2, WD(SC + 17 + mm), Wmv, 17 + mm, aV);
        add_v_row(v1 * a1[2] - v2 * a1[1], v2 * a1[0] - v0 * a1[2], v0 * a1[1] - v1 * a1[0],
                  WD(SC + 26 + mm), Wmv, 26 + mm, aV);
        add_v_row(A00 * v0 + A01 * v1 + A02 * v2, A01 * v0 + A11 * v1 + A12 * v2,
                  A02 * v0 + A12 * v1 + A22 * v2, WD(SC + 35 + mm), Wmv, 35 + mm, aV);
        to5_add(v0 * a1[0], v0 * a1[1], v0 * a1[2],
                v1 * a1[0], v1 * a1[1], v1 * a1[2],
                v2 * a1[0], v2 * a1[1], v2 * a1[2],
                WD(SC + VC + 17 + mm), Wmt, 17 + mm, aT);
        float C200 = v1 * A02 - v2 * A01, C210 = v2 * A00 - v0 * A02, C220 = v0 * A01 - v1 * A00;
        float C201 = v1 * A12 - v2 * A11, C211 = v2 * A01 - v0 * A12, C221 = v0 * A11 - v1 * A01;
        float C202 = v1 * A22 - v2 * A12, C212 = v2 * A02 - v0 * A22, C222 = v0 * A12 - v1 * A02;
        to5_add(C200, C201, C202, C210, C211, C212, C220, C221, C222,
                WD(SC + VC + 26 + mm), Wmt, 26 + mm, aT);
    }

    // tensor block: mm = 0..4
#pragma unroll
    for (int mm = 0; mm < 5; mm++) {
        float t0 = mt[mm][0], t1 = mt[mm][1], t2 = mt[mm][2], t3 = mt[mm][3], t4 = mt[mm][4];
        float T00 = -RC6 * t2 + RC2 * t4, T01 = RC2 * t0, T02 = RC2 * t3;
        float T11 = -RC6 * t2 - RC2 * t4, T12 = RC2 * t1, T22 = 2.f * RC6 * t2;
        float P00 = T00 * A00 + T01 * A01 + T02 * A02;
        float P01 = T00 * A01 + T01 * A11 + T02 * A12;
        float P02 = T00 * A02 + T01 * A12 + T02 * A22;
        float P10 = T01 * A00 + T11 * A01 + T12 * A02;
        float P11 = T01 * A01 + T11 * A11 + T12 * A12;
        float P12 = T01 * A02 + T11 * A12 + T12 * A22;
        float P20 = T02 * A00 + T12 * A01 + T22 * A02;
        float P21 = T02 * A01 + T12 * A11 + T22 * A12;
        float P22 = T02 * A02 + T12 * A12 + T22 * A22;
        add_s_row(P00 + P11 + P22, WD(26 + mm), Wms, 26 + mm, aS);
        add_v_row(T00 * a1[0] + T01 * a1[1] + T02 * a1[2],
                  T01 * a1[0] + T11 * a1[1] + T12 * a1[2],
                  T02 * a1[0] + T12 * a1[1] + T22 * a1[2],
                  WD(SC + 44 + mm), Wmv, 44 + mm, aV);
        add_v_row(P12 - P21, P20 - P02, P01 - P10, WD(SC + 49 + mm), Wmv, 49 + mm, aV);
        add_t_row(t0, t1, t2, t3, t4, WD(SC + VC + 35 + mm), Wmt, 35 + mm, aT);
        float u0 = a1[0], u1 = a1[1], u2 = a1[2];
        float C300 = u1 * T02 - u2 * T01, C310 = u2 * T00 - u0 * T02, C320 = u0 * T01 - u1 * T00;
        float C301 = u1 * T12 - u2 * T11, C311 = u2 * T01 - u0 * T12, C321 = u0 * T11 - u1 * T01;
        float C302 = u1 * T22 - u2 * T12, C312 = u2 * T02 - u0 * T22, C322 = u0 * T12 - u1 * T02;
        to5_add(C300, C301, C302, C310, C311, C312, C320, C321, C322,
                WD(SC + VC + 40 + mm), Wmt, 40 + mm, aT);
        to5_add(P00, P01, P02, P10, P11, P12, P20, P21, P22,
                WD(SC + VC + 45 + mm), Wmt, 45 + mm, aT);
    }
#undef WD

    // ---- store message in EDGE order (padded 320B rows, 64B-aligned) ----
    float4* mrow = (float4*)(msg + (size_t)e * MSTRIDE);
    const float kS = 0.17960530202677491f;  // 1/sqrt(31)
    const float kV = 0.13608276348795434f;  // 1/sqrt(54)
    const float kT = 0.1414213562373095f;   // 1/sqrt(50)
#pragma unroll
    for (int i = 0; i < 7; i++) {
        float4 q;
        q.x = aS[4 * i] * kS; q.y = aS[4 * i + 1] * kS;
        q.z = aS[4 * i + 2] * kS; q.w = aS[4 * i + 3] * kS;
        mrow[i] = q;
    }
    const float* av = &aV[0][0];
#pragma unroll
    for (int i = 0; i < 6; i++) {
        float4 q;
        q.x = av[4 * i] * kV; q.y = av[4 * i + 1] * kV;
        q.z = av[4 * i + 2] * kV; q.w = av[4 * i + 3] * kV;
        mrow[7 + i] = q;
    }
    const float* at = &aT[0][0];
#pragma unroll
    for (int i = 0; i < 5; i++) {
        float4 q;
        q.x = at[4 * i] * kT; q.y = at[4 * i + 1] * kT;
        q.z = at[4 * i + 2] * kT; q.w = at[4 * i + 3] * kT;
        mrow[13 + i] = q;
    }
}

// ================= gather: wave per node, 18-lane coalesced row reads =================
__global__ __launch_bounds__(256) void gather_kernel(
    const float4* __restrict__ msg4, const int* __restrict__ offs,
    const int* __restrict__ elist, float4* __restrict__ agg4)
{
    int wid = threadIdx.x >> 6;
    int lane = threadIdx.x & 63;
    int n = blockIdx.x * 4 + wid;
    if (n >= NN) return;                 // wave-uniform exit
    int sub = lane / 18;                 // 0..2 active, 3 idle
    int q = lane - sub * 18;
    int beg = offs[n], end = offs[n + 1];
    float4 acc = {0.f, 0.f, 0.f, 0.f};
    if (sub < 3) {
        for (int j = beg + sub; j < end; j += 3) {
            int e = elist[j];
            float4 m = msg4[(size_t)e * (MSTRIDE / 4) + q];
            acc.x += m.x; acc.y += m.y; acc.z += m.z; acc.w += m.w;
        }
    }
    // reduce sub-groups: lane q takes lanes q+18, q+36
    float bx = __shfl(acc.x, lane + 18), by = __shfl(acc.y, lane + 18);
    float bz = __shfl(acc.z, lane + 18), bw = __shfl(acc.w, lane + 18);
    float cx = __shfl(acc.x, lane + 36), cy = __shfl(acc.y, lane + 36);
    float cz = __shfl(acc.z, lane + 36), cw = __shfl(acc.w, lane + 36);
    if (lane < 18) {
        float4 r;
        r.x = acc.x + bx + cx; r.y = acc.y + by + cy;
        r.z = acc.z + bz + cz; r.w = acc.w + bw + cw;
        agg4[(size_t)n * 18 + lane] = r;
    }
}

// ================= node update =================
__global__ __launch_bounds__(256) void node_kernel(
    const float* __restrict__ cur, const float* __restrict__ agg,
    const float* __restrict__ Wns, const float* __restrict__ Wnv, const float* __restrict__ Wnt,
    const float* __restrict__ Wps, const float* __restrict__ Wpv, const float* __restrict__ Wpt,
    float* __restrict__ dst)
{
    int n = blockIdx.x * 256 + threadIdx.x;
    if (n >= NN) return;
    const float* xn = cur + (size_t)n * FEAT;
    const float* ag = agg + (size_t)n * 72;
    const float invE = 0.0025f;  // 1/sqrt(160000)

    float msv[28];
#pragma unroll
    for (int o = 0; o < 28; o++) msv[o] = ag[o] * invE;
#pragma unroll
    for (int i = 0; i < 16; i++) {
        float si = xn[i] * 0.25f;
#pragma unroll
        for (int o = 0; o < 28; o++) msv[o] += si * Wns[i * 28 + o];
    }
    float mvv[8][3];
#pragma unroll
    for (int o = 0; o < 8; o++)
#pragma unroll
        for (int c = 0; c < 3; c++) mvv[o][c] = ag[28 + o * 3 + c] * invE;
#pragma unroll
    for (int i = 0; i < 8; i++)
#pragma unroll
        for (int o = 0; o < 8; o++) {
            float w = Wnv[i * 8 + o] * 0.3535533905932738f;
#pragma unroll
            for (int c = 0; c < 3; c++) mvv[o][c] += xn[16 + i * 3 + c] * w;
        }
    float mtv[4][5];
#pragma unroll
    for (int o = 0; o < 4; o++)
#pragma unroll
        for (int c = 0; c < 5; c++) mtv[o][c] = ag[52 + o * 5 + c] * invE;
#pragma unroll
    for (int i = 0; i < 4; i++)
#pragma unroll
        for (int o = 0; o < 4; o++) {
            float w = Wnt[i * 4 + o] * 0.5f;
#pragma unroll
            for (int c = 0; c < 5; c++) mtv[o][c] += xn[40 + i * 5 + c] * w;
        }

    float g[12];
#pragma unroll
    for (int j = 0; j < 12; j++) g[j] = sigmoidf_(msv[16 + j]);
    float hs[16];
#pragma unroll
    for (int i = 0; i < 16; i++) hs[i] = geluf(msv[i]);

    float outv[60];
#pragma unroll
    for (int o = 0; o < 16; o++) outv[o] = 0.f;
#pragma unroll
    for (int i = 0; i < 16; i++) {
        float si = hs[i] * 0.25f;
#pragma unroll
        for (int o = 0; o < 16; o++) outv[o] += si * Wps[i * 16 + o];
    }
#pragma unroll
    for (int o = 0; o < 8; o++)
#pragma unroll
        for (int c = 0; c < 3; c++) outv[16 + o * 3 + c] = 0.f;
#pragma unroll
    for (int i = 0; i < 8; i++) {
        float gi = g[i];
#pragma unroll
        for (int o = 0; o < 8; o++) {
            float w = Wpv[i * 8 + o] * 0.3535533905932738f * gi;
#pragma unroll
            for (int c = 0; c < 3; c++) outv[16 + o * 3 + c] += mvv[i][c] * w;
        }
    }
#pragma unroll
    for (int o = 0; o < 4; o++)
#pragma unroll
        for (int c = 0; c < 5; c++) outv[40 + o * 5 + c] = 0.f;
#pragma unroll
    for (int i = 0; i < 4; i++) {
        float gi = g[8 + i];
#pragma unroll
        for (int o = 0; o < 4; o++) {
            float w = Wpt[i * 4 + o] * 0.5f * gi;
#pragma unroll
            for (int c = 0; c < 5; c++) outv[40 + o * 5 + c] += mtv[i][c] * w;
        }
    }

    float4* dst4 = (float4*)(dst + (size_t)n * FEAT);
#pragma unroll
    for (int i = 0; i < 15; i++) {
        float4 q;
        q.x = outv[4 * i]; q.y = outv[4 * i + 1]; q.z = outv[4 * i + 2]; q.w = outv[4 * i + 3];
        dst4[i] = q;
    }
}

// ================= host =================
extern "C" void kernel_launch(void* const* d_in, const int* in_sizes, int n_in,
                              void* d_out, int out_size, void* d_ws, size_t ws_size,
                              hipStream_t stream)
{
    const float* x    = (const float*)d_in[0];
    const float* Wl_s = (const float*)d_in[1];
    const float* Wl_v = (const float*)d_in[2];
    const float* Wl_t = (const float*)d_in[3];
    const float* Wr0  = (const float*)d_in[4];
    const float* Wr1  = (const float*)d_in[5];
    const float* Wr2  = (const float*)d_in[6];
    const float* Wr3  = (const float*)d_in[7];
    const float* Wm_s = (const float*)d_in[8];
    const float* Wm_v = (const float*)d_in[9];
    const float* Wm_t = (const float*)d_in[10];
    const float* Wn_s = (const float*)d_in[11];
    const float* Wn_v = (const float*)d_in[12];
    const float* Wn_t = (const float*)d_in[13];
    const float* Wp_s = (const float*)d_in[14];
    const float* Wp_v = (const float*)d_in[15];
    const float* Wp_t = (const float*)d_in[16];
    const int* snd = (const int*)d_in[17];
    const int* rcv = (const int*)d_in[18];
    float* out = (float*)d_out;

    char* ws = (char*)d_ws;
    size_t off = 0;
    float* cur    = (float*)(ws + off); off += (size_t)NN * FEAT * 4;            // 2,400,000
    float* agg    = (float*)(ws + off); off += (size_t)NN * 72 * 4;              // 2,880,000
    float* msg    = (float*)(ws + off); off += (size_t)NE * MSTRIDE * 4;         // 51,200,000
    int*   counts = (int*)(ws + off);   off += (size_t)NN * 4;                   // 40,000
    int*   offs   = (int*)(ws + off);   off += (size_t)(NN + 1) * 4 + 12;        // 40,016
    int*   rank   = (int*)(ws + off);   off += (size_t)NE * 4;                   // 640,000
    int*   elist  = (int*)(ws + off);   off += (size_t)NE * 4;                   // 640,000
    float* W3t    = (float*)(ws + off); off += (size_t)3 * NIR * DH * 4;         // 103,680
    // per-chunk buffers: h2 (64*ce) + h3 (64*ce) + w (135*ce)
    size_t avail = (ws_size > off) ? (ws_size - off) : 0;
    long long chunkE = (long long)(avail / ((size_t)(DH + DH + NIR) * sizeof(float)));
    chunkE &= ~255LL;
    if (chunkE > NE) chunkE = NE;
    if (chunkE < 4096) chunkE = 4096;
    float* h2buf = (float*)(ws + off);
    float* h3buf = h2buf + (size_t)DH * chunkE;
    float* wbuf  = h3buf + (size_t)DH * chunkE;

    hipMemcpyAsync(cur, x, (size_t)NN * FEAT * 4, hipMemcpyDeviceToDevice, stream);
    hipMemsetAsync(counts, 0, (size_t)NN * 4, stream);
    csr_hist<<<(NE + 255) / 256, 256, 0, stream>>>(rcv, counts, rank);
    csr_scan<<<1, 1024, 0, stream>>>(counts, offs);
    csr_fill<<<(NE + 255) / 256, 256, 0, stream>>>(rcv, offs, rank, elist);
    w3t_kernel<<<(3 * NIR * DH + 255) / 256, 256, 0, stream>>>(Wr3, W3t);

    for (int k = 0; k < 3; k++) {
        const float* W0  = Wr0 + (size_t)k * 4 * DH;
        const float* W1  = Wr1 + (size_t)k * DH * DH;
        const float* W2  = Wr2 + (size_t)k * DH * DH;
        const float* W3tk= W3t + (size_t)k * NIR * DH;
        const float* Wls = Wl_s + (size_t)k * 16 * 16;
        const float* Wlv = Wl_v + (size_t)k * 8 * 8;
        const float* Wlt = Wl_t + (size_t)k * 4 * 4;
        const float* Wms = Wm_s + (size_t)k * SC * 28;
        const float* Wmv = Wm_v + (size_t)k * VC * 8;
        const float* Wmt = Wm_t + (size_t)k * TC * 4;
        const float* Wns = Wn_s + (size_t)k * 16 * 28;
        const float* Wnv = Wn_v + (size_t)k * 8 * 8;
        const float* Wnt = Wn_t + (size_t)k * 4 * 4;
        const float* Wps = Wp_s + (size_t)k * 16 * 16;
        const float* Wpv = Wp_v + (size_t)k * 8 * 8;
        const float* Wpt = Wp_t + (size_t)k * 4 * 4;

        for (long long e0 = 0; e0 < NE; e0 += chunkE) {
            long long e1 = e0 + chunkE; if (e1 > NE) e1 = NE;
            long long n = e1 - e0;
            int nb = (int)((n + 255) / 256);
            r01_kernel<<<nb, 256, 0, stream>>>(cur, snd, rcv, W0, W1,
                                               h2buf, (int)e0, (int)e1, (int)chunkE);
            r2_kernel<<<nb, 256, 0, stream>>>(W2, h2buf, h3buf, (int)n, (int)chunkE);
            r3_kernel<<<nb, 256, 0, stream>>>(W3tk, h3buf, wbuf, (int)n, (int)chunkE);
            tp_kernel<<<nb, 256, 0, stream>>>(cur, snd, rcv, Wls, Wlv, Wlt,
                                              Wms, Wmv, Wmt, wbuf, msg,
                                              (int)e0, (int)e1, (int)chunkE);
        }
        gather_kernel<<<(NN + 3) / 4, 256, 0, stream>>>(
            (const float4*)msg, offs, elist, (float4*)agg);
        float* dst = (k == 2) ? out : cur;
        node_kernel<<<(NN + 255) / 256, 256, 0, stream>>>(cur, agg, Wns, Wnv, Wnt,
                                                          Wps, Wpv, Wpt, dst);
    }
}

// Round 8
// 1069.813 us; speedup vs baseline: 2.6806x; 1.3099x over previous
//
#include <hip/hip_runtime.h>
#include <math.h>

#define DEV __device__ __forceinline__

#define NN 10000
#define NE 160000
#define DH 64
#define SC 31
#define VC 54
#define TC 50
#define NIR 135
#define FEAT 60
#define MSTRIDE 80   // padded msg row (floats)

DEV float rcpf(float x) { return __builtin_amdgcn_rcpf(x); }

DEV float geluf(float x) {
    float u = 0.7978845608028654f * (x + 0.044715f * x * x * x);
    u = fminf(fmaxf(u, -9.f), 9.f);
    float e = __expf(2.f * u);
    float th = (e - 1.f) * rcpf(e + 1.f);
    return 0.5f * x * (1.f + th);
}
DEV float sigmoidf_(float x) { return rcpf(1.f + __expf(-x)); }

// ================= CSR build (once per launch) =================
__global__ __launch_bounds__(256) void csr_hist(const int* __restrict__ rcv,
                                                int* __restrict__ counts,
                                                int* __restrict__ rank) {
    int e = blockIdx.x * 256 + threadIdx.x;
    if (e >= NE) return;
    rank[e] = atomicAdd(&counts[rcv[e]], 1);
}

__global__ __launch_bounds__(1024) void csr_scan(const int* __restrict__ counts,
                                                 int* __restrict__ offs) {
    __shared__ int buf[1024];
    __shared__ int carry_s;
    if (threadIdx.x == 0) carry_s = 0;
    __syncthreads();
    for (int base = 0; base < 10240; base += 1024) {
        int i = base + threadIdx.x;
        int v = (i < NN) ? counts[i] : 0;
        buf[threadIdx.x] = v;
        __syncthreads();
        for (int off = 1; off < 1024; off <<= 1) {
            int t = (threadIdx.x >= off) ? buf[threadIdx.x - off] : 0;
            __syncthreads();
            buf[threadIdx.x] += t;
            __syncthreads();
        }
        int cbase = carry_s;
        int incl = buf[threadIdx.x];
        if (i < NN) offs[i] = cbase + incl - v;
        int total = buf[1023];
        __syncthreads();
        if (threadIdx.x == 0) carry_s = cbase + total;
        __syncthreads();
    }
    if (threadIdx.x == 0) offs[NN] = carry_s;
}

__global__ __launch_bounds__(256) void csr_fill(const int* __restrict__ rcv,
                                                const int* __restrict__ offs,
                                                const int* __restrict__ rank,
                                                int* __restrict__ elist) {
    int e = blockIdx.x * 256 + threadIdx.x;
    if (e >= NE) return;
    elist[offs[rcv[e]] + rank[e]] = e;
}

// ================= W3 transpose (once per launch) =================
__global__ __launch_bounds__(256) void w3t_kernel(const float* __restrict__ Wr3,
                                                  float* __restrict__ W3t) {
    int t = blockIdx.x * 256 + threadIdx.x;
    if (t >= 3 * NIR * DH) return;
    int k = t / (NIR * DH), r = t % (NIR * DH);
    int i = r / DH, j = r % DH;
    W3t[t] = Wr3[k * DH * NIR + j * NIR + i];
}

// ================= r01: R4 -> h1 -> half of h2 =================
__global__ __launch_bounds__(256) void r01_kernel(
    const float* __restrict__ cur, const int* __restrict__ snd, const int* __restrict__ rcv,
    const float* __restrict__ W0, const float* __restrict__ W1,
    float* __restrict__ h2out, int e0, int e1, int ce, int nbh)
{
    int half = blockIdx.x / nbh;
    int e = e0 + (blockIdx.x - half * nbh) * 256 + threadIdx.x;
    if (e >= e1) return;
    int is = snd[e], ir = rcv[e];
    float4 qs = ((const float4*)(cur + (size_t)is * FEAT))[4];
    float4 qr = ((const float4*)(cur + (size_t)ir * FEAT))[4];
    float rx = qs.x - qr.x, ry = qs.y - qr.y, rz = qs.z - qr.z;
    float d = sqrtf(rx * rx + ry * ry + rz * rz);
    float ds = fmaxf(d, 1e-9f);
    float rinv = 1.f / ds;
    float R4[4];
#pragma unroll
    for (int b = 0; b < 4; b++)
        R4[b] = sinf((float)(b + 1) * 1.5707963267948966f * ds) * rinv;

    float h1[DH];
#pragma unroll
    for (int o = 0; o < DH; o++)
        h1[o] = geluf((R4[0] * W0[o] + R4[1] * W0[DH + o] +
                      R4[2] * W0[2 * DH + o] + R4[3] * W0[3 * DH + o]) * 0.5f);

    int eo = e - e0;
#pragma unroll
    for (int cc = 0; cc < 2; cc++) {
        int c4 = half * 2 + cc;
        float acc[16];
#pragma unroll
        for (int o = 0; o < 16; o++) acc[o] = h1[0] * W1[c4 * 16 + o];
#pragma unroll
        for (int j = 1; j < DH; j++)
#pragma unroll
            for (int o = 0; o < 16; o++) acc[o] += h1[j] * W1[j * DH + c4 * 16 + o];
#pragma unroll
        for (int o = 0; o < 16; o++)
            h2out[(size_t)(c4 * 16 + o) * ce + eo] = geluf(acc[o] * 0.125f);
    }
}

// ================= r2: h2 -> half of h3 =================
__global__ __launch_bounds__(256) void r2_kernel(
    const float* __restrict__ W2, const float* __restrict__ h2buf,
    float* __restrict__ h3out, int ne, int ce, int nbh)
{
    int half = blockIdx.x / nbh;
    int eo = (blockIdx.x - half * nbh) * 256 + threadIdx.x;
    if (eo >= ne) return;
    float h2[DH];
#pragma unroll
    for (int j = 0; j < DH; j++) h2[j] = h2buf[(size_t)j * ce + eo];

#pragma unroll
    for (int cc = 0; cc < 2; cc++) {
        int c4 = half * 2 + cc;
        float acc[16];
#pragma unroll
        for (int o = 0; o < 16; o++) acc[o] = h2[0] * W2[c4 * 16 + o];
#pragma unroll
        for (int j = 1; j < DH; j++)
#pragma unroll
            for (int o = 0; o < 16; o++) acc[o] += h2[j] * W2[j * DH + c4 * 16 + o];
#pragma unroll
        for (int o = 0; o < 16; o++)
            h3out[(size_t)(c4 * 16 + o) * ce + eo] = geluf(acc[o] * 0.125f);
    }
}

// ================= r3: h3 -> half of 135 radial weights =================
__global__ __launch_bounds__(256) void r3_kernel(
    const float* __restrict__ W3t, const float* __restrict__ h3buf,
    float* __restrict__ wout, int ne, int ce, int nbh)
{
    int half = blockIdx.x / nbh;
    int eo = (blockIdx.x - half * nbh) * 256 + threadIdx.x;
    if (eo >= ne) return;
    float h3[DH];
#pragma unroll
    for (int j = 0; j < DH; j++) h3[j] = h3buf[(size_t)j * ce + eo];

    int i0 = half ? 68 : 0;
    int i1 = half ? NIR : 68;
    for (int i = i0; i < i1; i++) {
        const float* col = W3t + (size_t)i * DH;
        float s0 = 0.f, s1 = 0.f;
#pragma unroll
        for (int j = 0; j < DH; j += 2) {
            s0 += h3[j] * col[j];
            s1 += h3[j + 1] * col[j + 1];
        }
        wout[(size_t)i * ce + eo] = (s0 + s1) * 0.125f;
    }
}

// ================= tp3: fat-grid 3-pass TP + projection =================
#define RC2 0.7071067811865476f
#define RC6 0.40824829046386302f

__global__ __launch_bounds__(256) void tp3_kernel(
    const float* __restrict__ cur, const int* __restrict__ snd, const int* __restrict__ rcv,
    const float* __restrict__ Wls, const float* __restrict__ Wlv, const float* __restrict__ Wlt,
    const float* __restrict__ Wms, const float* __restrict__ Wmv, const float* __restrict__ Wmt,
    const float* __restrict__ wp, float* __restrict__ msg, int e0, int e1, int ce, int nbp)
{
    int pass = blockIdx.x / nbp;
    int e = e0 + (blockIdx.x - pass * nbp) * 256 + threadIdx.x;
    if (e >= e1) return;
    int is = snd[e], ir = rcv[e];
    int eo = e - e0;
    const float* xs = cur + (size_t)is * FEAT;

    // geometry (all passes)
    float4 qs = ((const float4*)xs)[4];
    float4 qr = ((const float4*)(cur + (size_t)ir * FEAT))[4];
    float rx = qs.x - qr.x, ry = qs.y - qr.y, rz = qs.z - qr.z;
    float d = sqrtf(rx * rx + ry * ry + rz * rz);
    float dsafe = fmaxf(d, 1e-9f);
    float rinv = 1.f / dsafe;
    float nx = rx * rinv, ny = ry * rinv, nz = rz * rinv;
    float a1[3] = {1.7320508075688772f * nx, 1.7320508075688772f * ny, 1.7320508075688772f * nz};
    float a2[5] = {3.872983346207417f * nx * ny,
                   3.872983346207417f * ny * nz,
                   1.118033988749895f * (3.f * nz * nz - 1.f),
                   3.872983346207417f * nx * nz,
                   1.9364916731037085f * (nx * nx - ny * ny)};

#define WD(i) (wp[(size_t)(i) * ce + eo])
    float4* mrow = (float4*)(msg + (size_t)e * MSTRIDE);

    // ms = s_snd @ Wls / 4 (all passes need it)
    float ms[16];
    {
        float sb[16];
        const float4* p4 = (const float4*)xs;
#pragma unroll
        for (int i = 0; i < 4; i++) {
            float4 q = p4[i];
            sb[4 * i] = q.x; sb[4 * i + 1] = q.y; sb[4 * i + 2] = q.z; sb[4 * i + 3] = q.w;
        }
#pragma unroll
        for (int o = 0; o < 16; o++) ms[o] = 0.f;
#pragma unroll
        for (int i = 0; i < 16; i++) {
            float si = sb[i];
#pragma unroll
            for (int o = 0; o < 16; o++) ms[o] += si * Wls[i * 16 + o];
        }
#pragma unroll
        for (int o = 0; o < 16; o++) ms[o] *= 0.25f;
    }

    if (pass == 0) {
        // ================= Pass S (reduced algebra) =================
        float aS[28];
#pragma unroll
        for (int o = 0; o < 28; o++) aS[o] = 0.f;
        // rows 0..16
#pragma unroll
        for (int i = 0; i < 17; i++) {
            float sm = ((i < 16) ? ms[i] : 1.f) * WD(i);
#pragma unroll
            for (int o = 0; o < 28; o++) aS[o] += sm * Wms[i * 28 + o];
        }
        // rows 17..25: dot(mv_row, a1) via per-row dots
        {
            float db[8];
            const float4* p4 = (const float4*)(xs + 16);
            float vb[24];
#pragma unroll
            for (int i = 0; i < 6; i++) {
                float4 q = p4[i];
                vb[4 * i] = q.x; vb[4 * i + 1] = q.y; vb[4 * i + 2] = q.z; vb[4 * i + 3] = q.w;
            }
#pragma unroll
            for (int i = 0; i < 8; i++)
                db[i] = vb[i * 3] * a1[0] + vb[i * 3 + 1] * a1[1] + vb[i * 3 + 2] * a1[2];
#pragma unroll
            for (int mm = 0; mm < 9; mm++) {
                float sval;
                if (mm < 8) {
                    sval = 0.f;
#pragma unroll
                    for (int i = 0; i < 8; i++) sval += db[i] * Wlv[i * 8 + mm];
                    sval *= 0.3535533905932738f;
                } else {
                    sval = a1[0] * a1[0] + a1[1] * a1[1] + a1[2] * a1[2];
                }
                float sm = sval * WD(17 + mm);
#pragma unroll
                for (int o = 0; o < 28; o++) aS[o] += sm * Wms[(17 + mm) * 28 + o];
            }
        }
        // rows 26..30: tr(T·A) = t_row · a2 (basis orthonormality)
        {
            float dt[4];
            const float4* p4 = (const float4*)(xs + 40);
            float tb[20];
#pragma unroll
            for (int i = 0; i < 5; i++) {
                float4 q = p4[i];
                tb[4 * i] = q.x; tb[4 * i + 1] = q.y; tb[4 * i + 2] = q.z; tb[4 * i + 3] = q.w;
            }
#pragma unroll
            for (int i = 0; i < 4; i++)
                dt[i] = tb[i * 5] * a2[0] + tb[i * 5 + 1] * a2[1] + tb[i * 5 + 2] * a2[2] +
                        tb[i * 5 + 3] * a2[3] + tb[i * 5 + 4] * a2[4];
#pragma unroll
            for (int mm = 0; mm < 5; mm++) {
                float sval;
                if (mm < 4) {
                    sval = 0.f;
#pragma unroll
                    for (int i = 0; i < 4; i++) sval += dt[i] * Wlt[i * 4 + mm];
                    sval *= 0.5f;
                } else {
                    sval = a2[0] * a2[0] + a2[1] * a2[1] + a2[2] * a2[2] + a2[3] * a2[3] + a2[4] * a2[4];
                }
                float sm = sval * WD(26 + mm);
#pragma unroll
                for (int o = 0; o < 28; o++) aS[o] += sm * Wms[(26 + mm) * 28 + o];
            }
        }
        const float kS = 0.17960530202677491f;
#pragma unroll
        for (int i = 0; i < 7; i++) {
            float4 q;
            q.x = aS[4 * i] * kS; q.y = aS[4 * i + 1] * kS;
            q.z = aS[4 * i + 2] * kS; q.w = aS[4 * i + 3] * kS;
            mrow[i] = q;
        }
        return;
    }

    // A = to_mat(a2), symmetric (passes V,T)
    float A00 = -RC6 * a2[2] + RC2 * a2[4];
    float A01 = RC2 * a2[0];
    float A02 = RC2 * a2[3];
    float A11 = -RC6 * a2[2] - RC2 * a2[4];
    float A12 = RC2 * a2[1];
    float A22 = 2.f * RC6 * a2[2];

    // mv (passes V,T)
    float mv[9][3];
    {
        float vb[24];
        const float4* p4 = (const float4*)(xs + 16);
#pragma unroll
        for (int i = 0; i < 6; i++) {
            float4 q = p4[i];
            vb[4 * i] = q.x; vb[4 * i + 1] = q.y; vb[4 * i + 2] = q.z; vb[4 * i + 3] = q.w;
        }
#pragma unroll
        for (int o = 0; o < 8; o++) { mv[o][0] = 0.f; mv[o][1] = 0.f; mv[o][2] = 0.f; }
#pragma unroll
        for (int i = 0; i < 8; i++)
#pragma unroll
            for (int o = 0; o < 8; o++) {
                float w = Wlv[i * 8 + o];
                mv[o][0] += vb[i * 3 + 0] * w;
                mv[o][1] += vb[i * 3 + 1] * w;
                mv[o][2] += vb[i * 3 + 2] * w;
            }
#pragma unroll
        for (int o = 0; o < 8; o++) {
            mv[o][0] *= 0.3535533905932738f; mv[o][1] *= 0.3535533905932738f; mv[o][2] *= 0.3535533905932738f;
        }
        mv[8][0] = a1[0]; mv[8][1] = a1[1]; mv[8][2] = a1[2];
    }

    // mt (passes V,T)
    float mt[5][5];
    {
        float tb[20];
        const float4* p4 = (const float4*)(xs + 40);
#pragma unroll
        for (int i = 0; i < 5; i++) {
            float4 q = p4[i];
            tb[4 * i] = q.x; tb[4 * i + 1] = q.y; tb[4 * i + 2] = q.z; tb[4 * i + 3] = q.w;
        }
#pragma unroll
        for (int o = 0; o < 4; o++)
#pragma unroll
            for (int c = 0; c < 5; c++) mt[o][c] = 0.f;
#pragma unroll
        for (int i = 0; i < 4; i++)
#pragma unroll
            for (int o = 0; o < 4; o++) {
                float w = Wlt[i * 4 + o];
#pragma unroll
                for (int c = 0; c < 5; c++) mt[o][c] += tb[i * 5 + c] * w;
            }
#pragma unroll
        for (int o = 0; o < 4; o++)
#pragma unroll
            for (int c = 0; c < 5; c++) mt[o][c] *= 0.5f;
#pragma unroll
        for (int c = 0; c < 5; c++) mt[4][c] = a2[c];
    }

    if (pass == 1) {
        // ================= Pass V =================
        float aV[24];
#pragma unroll
        for (int o = 0; o < 24; o++) aV[o] = 0.f;
#define ADDV(vx, vy, vz, wm, row)                                           \
        {                                                                   \
            float _x = (vx) * (wm), _y = (vy) * (wm), _z = (vz) * (wm);     \
            _Pragma("unroll")                                               \
            for (int o = 0; o < 8; o++) {                                   \
                float w = Wmv[(row) * 8 + o];                               \
                aV[o * 3] += _x * w; aV[o * 3 + 1] += _y * w; aV[o * 3 + 2] += _z * w; \
            }                                                               \
        }
#pragma unroll
        for (int i = 0; i < 17; i++) {
            float mi = (i < 16) ? ms[i] : 1.f;
            ADDV(mi * a1[0], mi * a1[1], mi * a1[2], WD(SC + i), i);
        }
#pragma unroll
        for (int mm = 0; mm < 9; mm++) {
            float v0 = mv[mm][0], v1 = mv[mm][1], v2 = mv[mm][2];
            ADDV(v0, v1, v2, WD(SC + 17 + mm), 17 + mm);
            ADDV(v1 * a1[2] - v2 * a1[1], v2 * a1[0] - v0 * a1[2], v0 * a1[1] - v1 * a1[0],
                 WD(SC + 26 + mm), 26 + mm);
            ADDV(A00 * v0 + A01 * v1 + A02 * v2, A01 * v0 + A11 * v1 + A12 * v2,
                 A02 * v0 + A12 * v1 + A22 * v2, WD(SC + 35 + mm), 35 + mm);
        }
#pragma unroll
        for (int mm = 0; mm < 5; mm++) {
            float t0 = mt[mm][0], t1 = mt[mm][1], t2 = mt[mm][2], t3 = mt[mm][3], t4 = mt[mm][4];
            float T00 = -RC6 * t2 + RC2 * t4, T01 = RC2 * t0, T02 = RC2 * t3;
            float T11 = -RC6 * t2 - RC2 * t4, T12 = RC2 * t1, T22 = 2.f * RC6 * t2;
            ADDV(T00 * a1[0] + T01 * a1[1] + T02 * a1[2],
                 T01 * a1[0] + T11 * a1[1] + T12 * a1[2],
                 T02 * a1[0] + T12 * a1[1] + T22 * a1[2], WD(SC + 44 + mm), 44 + mm);
            float P01 = T00 * A01 + T01 * A11 + T02 * A12;
            float P02 = T00 * A02 + T01 * A12 + T02 * A22;
            float P10 = T01 * A00 + T11 * A01 + T12 * A02;
            float P12 = T01 * A02 + T11 * A12 + T12 * A22;
            float P20 = T02 * A00 + T12 * A01 + T22 * A02;
            float P21 = T02 * A01 + T12 * A11 + T22 * A12;
            ADDV(P12 - P21, P20 - P02, P01 - P10, WD(SC + 49 + mm), 49 + mm);
        }
#undef ADDV
        const float kV = 0.13608276348795434f;
#pragma unroll
        for (int i = 0; i < 6; i++) {
            float4 q;
            q.x = aV[4 * i] * kV; q.y = aV[4 * i + 1] * kV;
            q.z = aV[4 * i + 2] * kV; q.w = aV[4 * i + 3] * kV;
            mrow[7 + i] = q;
        }
        return;
    }

    // ================= Pass T =================
    {
        float aT[20];
#pragma unroll
        for (int o = 0; o < 20; o++) aT[o] = 0.f;
#define ADDT(u0, u1, u2, u3, u4, wm, row)                                   \
        {                                                                   \
            float _0 = (u0) * (wm), _1 = (u1) * (wm), _2 = (u2) * (wm),     \
                  _3 = (u3) * (wm), _4 = (u4) * (wm);                       \
            _Pragma("unroll")                                               \
            for (int o = 0; o < 4; o++) {                                   \
                float w = Wmt[(row) * 4 + o];                               \
                aT[o * 5] += _0 * w; aT[o * 5 + 1] += _1 * w;               \
                aT[o * 5 + 2] += _2 * w; aT[o * 5 + 3] += _3 * w;           \
                aT[o * 5 + 4] += _4 * w;                                    \
            }                                                               \
        }
#define TO5T(M00, M01, M02, M10, M11, M12, M20, M21, M22, wm, row)          \
        ADDT(RC2 * ((M01) + (M10)), RC2 * ((M12) + (M21)),                  \
             RC6 * (-(M00) - (M11) + 2.f * (M22)),                         \
             RC2 * ((M02) + (M20)), RC2 * ((M00) - (M11)), wm, row)
#pragma unroll
        for (int i = 0; i < 17; i++) {
            float mi = (i < 16) ? ms[i] : 1.f;
            ADDT(mi * a2[0], mi * a2[1], mi * a2[2], mi * a2[3], mi * a2[4],
                 WD(SC + VC + i), i);
        }
#pragma unroll
        for (int mm = 0; mm < 9; mm++) {
            float v0 = mv[mm][0], v1 = mv[mm][1], v2 = mv[mm][2];
            TO5T(v0 * a1[0], v0 * a1[1], v0 * a1[2],
                 v1 * a1[0], v1 * a1[1], v1 * a1[2],
                 v2 * a1[0], v2 * a1[1], v2 * a1[2],
                 WD(SC + VC + 17 + mm), 17 + mm);
            float C200 = v1 * A02 - v2 * A01, C210 = v2 * A00 - v0 * A02, C220 = v0 * A01 - v1 * A00;
            float C201 = v1 * A12 - v2 * A11, C211 = v2 * A01 - v0 * A12, C221 = v0 * A11 - v1 * A01;
            float C202 = v1 * A22 - v2 * A12, C212 = v2 * A02 - v0 * A22, C222 = v0 * A12 - v1 * A02;
            TO5T(C200, C201, C202, C210, C211, C212, C220, C221, C222,
                 WD(SC + VC + 26 + mm), 26 + mm);
        }
#pragma unroll
        for (int mm = 0; mm < 5; mm++) {
            float t0 = mt[mm][0], t1 = mt[mm][1], t2 = mt[mm][2], t3 = mt[mm][3], t4 = mt[mm][4];
            ADDT(t0, t1, t2, t3, t4, WD(SC + VC + 35 + mm), 35 + mm);
            float T00 = -RC6 * t2 + RC2 * t4, T01 = RC2 * t0, T02 = RC2 * t3;
            float T11 = -RC6 * t2 - RC2 * t4, T12 = RC2 * t1, T22 = 2.f * RC6 * t2;
            float u0 = a1[0], u1 = a1[1], u2 = a1[2];
            float C300 = u1 * T02 - u2 * T01, C310 = u2 * T00 - u0 * T02, C320 = u0 * T01 - u1 * T00;
            float C301 = u1 * T12 - u2 * T11, C311 = u2 * T01 - u0 * T12, C321 = u0 * T11 - u1 * T01;
            float C302 = u1 * T22 - u2 * T12, C312 = u2 * T02 - u0 * T22, C322 = u0 * T12 - u1 * T02;
            TO5T(C300, C301, C302, C310, C311, C312, C320, C321, C322,
                 WD(SC + VC + 40 + mm), 40 + mm);
            float P00 = T00 * A00 + T01 * A01 + T02 * A02;
            float P01 = T00 * A01 + T01 * A11 + T02 * A12;
            float P02 = T00 * A02 + T01 * A12 + T02 * A22;
            float P10 = T01 * A00 + T11 * A01 + T12 * A02;
            float P11 = T01 * A01 + T11 * A11 + T12 * A12;
            float P12 = T01 * A02 + T11 * A12 + T12 * A22;
            float P20 = T02 * A00 + T12 * A01 + T22 * A02;
            float P21 = T02 * A01 + T12 * A11 + T22 * A12;
            float P22 = T02 * A02 + T12 * A12 + T22 * A22;
            TO5T(P00, P01, P02, P10, P11, P12, P20, P21, P22,
                 WD(SC + VC + 45 + mm), 45 + mm);
        }
#undef TO5T
#undef ADDT
        const float kT = 0.1414213562373095f;
#pragma unroll
        for (int i = 0; i < 5; i++) {
            float4 q;
            q.x = aT[4 * i] * kT; q.y = aT[4 * i + 1] * kT;
            q.z = aT[4 * i + 2] * kT; q.w = aT[4 * i + 3] * kT;
            mrow[13 + i] = q;
        }
    }
#undef WD
}

// ================= gather: wave per node, 18-lane coalesced row reads =================
__global__ __launch_bounds__(256) void gather_kernel(
    const float4* __restrict__ msg4, const int* __restrict__ offs,
    const int* __restrict__ elist, float4* __restrict__ agg4)
{
    int wid = threadIdx.x >> 6;
    int lane = threadIdx.x & 63;
    int n = blockIdx.x * 4 + wid;
    if (n >= NN) return;
    int sub = lane / 18;
    int q = lane - sub * 18;
    int beg = offs[n], end = offs[n + 1];
    float4 acc = {0.f, 0.f, 0.f, 0.f};
    if (sub < 3) {
        for (int j = beg + sub; j < end; j += 3) {
            int e = elist[j];
            float4 m = msg4[(size_t)e * (MSTRIDE / 4) + q];
            acc.x += m.x; acc.y += m.y; acc.z += m.z; acc.w += m.w;
        }
    }
    float bx = __shfl(acc.x, lane + 18), by = __shfl(acc.y, lane + 18);
    float bz = __shfl(acc.z, lane + 18), bw = __shfl(acc.w, lane + 18);
    float cx = __shfl(acc.x, lane + 36), cy = __shfl(acc.y, lane + 36);
    float cz = __shfl(acc.z, lane + 36), cw = __shfl(acc.w, lane + 36);
    if (lane < 18) {
        float4 r;
        r.x = acc.x + bx + cx; r.y = acc.y + by + cy;
        r.z = acc.z + bz + cz; r.w = acc.w + bw + cw;
        agg4[(size_t)n * 18 + lane] = r;
    }
}

// ================= node update =================
__global__ __launch_bounds__(256) void node_kernel(
    const float* __restrict__ cur, const float* __restrict__ agg,
    const float* __restrict__ Wns, const float* __restrict__ Wnv, const float* __restrict__ Wnt,
    const float* __restrict__ Wps, const float* __restrict__ Wpv, const float* __restrict__ Wpt,
    float* __restrict__ dst)
{
    int n = blockIdx.x * 256 + threadIdx.x;
    if (n >= NN) return;
    const float* xn = cur + (size_t)n * FEAT;
    const float* ag = agg + (size_t)n * 72;
    const float invE = 0.0025f;

    float msv[28];
#pragma unroll
    for (int o = 0; o < 28; o++) msv[o] = ag[o] * invE;
#pragma unroll
    for (int i = 0; i < 16; i++) {
        float si = xn[i] * 0.25f;
#pragma unroll
        for (int o = 0; o < 28; o++) msv[o] += si * Wns[i * 28 + o];
    }
    float mvv[8][3];
#pragma unroll
    for (int o = 0; o < 8; o++)
#pragma unroll
        for (int c = 0; c < 3; c++) mvv[o][c] = ag[28 + o * 3 + c] * invE;
#pragma unroll
    for (int i = 0; i < 8; i++)
#pragma unroll
        for (int o = 0; o < 8; o++) {
            float w = Wnv[i * 8 + o] * 0.3535533905932738f;
#pragma unroll
            for (int c = 0; c < 3; c++) mvv[o][c] += xn[16 + i * 3 + c] * w;
        }
    float mtv[4][5];
#pragma unroll
    for (int o = 0; o < 4; o++)
#pragma unroll
        for (int c = 0; c < 5; c++) mtv[o][c] = ag[52 + o * 5 + c] * invE;
#pragma unroll
    for (int i = 0; i < 4; i++)
#pragma unroll
        for (int o = 0; o < 4; o++) {
            float w = Wnt[i * 4 + o] * 0.5f;
#pragma unroll
            for (int c = 0; c < 5; c++) mtv[o][c] += xn[40 + i * 5 + c] * w;
        }

    float g[12];
#pragma unroll
    for (int j = 0; j < 12; j++) g[j] = sigmoidf_(msv[16 + j]);
    float hs[16];
#pragma unroll
    for (int i = 0; i < 16; i++) hs[i] = geluf(msv[i]);

    float outv[60];
#pragma unroll
    for (int o = 0; o < 16; o++) outv[o] = 0.f;
#pragma unroll
    for (int i = 0; i < 16; i++) {
        float si = hs[i] * 0.25f;
#pragma unroll
        for (int o = 0; o < 16; o++) outv[o] += si * Wps[i * 16 + o];
    }
#pragma unroll
    for (int o = 0; o < 8; o++)
#pragma unroll
        for (int c = 0; c < 3; c++) outv[16 + o * 3 + c] = 0.f;
#pragma unroll
    for (int i = 0; i < 8; i++) {
        float gi = g[i];
#pragma unroll
        for (int o = 0; o < 8; o++) {
            float w = Wpv[i * 8 + o] * 0.3535533905932738f * gi;
#pragma unroll
            for (int c = 0; c < 3; c++) outv[16 + o * 3 + c] += mvv[i][c] * w;
        }
    }
#pragma unroll
    for (int o = 0; o < 4; o++)
#pragma unroll
        for (int c = 0; c < 5; c++) outv[40 + o * 5 + c] = 0.f;
#pragma unroll
    for (int i = 0; i < 4; i++) {
        float gi = g[8 + i];
#pragma unroll
        for (int o = 0; o < 4; o++) {
            float w = Wpt[i * 4 + o] * 0.5f * gi;
#pragma unroll
            for (int c = 0; c < 5; c++) outv[40 + o * 5 + c] += mtv[i][c] * w;
        }
    }

    float4* dst4 = (float4*)(dst + (size_t)n * FEAT);
#pragma unroll
    for (int i = 0; i < 15; i++) {
        float4 q;
        q.x = outv[4 * i]; q.y = outv[4 * i + 1]; q.z = outv[4 * i + 2]; q.w = outv[4 * i + 3];
        dst4[i] = q;
    }
}

// ================= host =================
extern "C" void kernel_launch(void* const* d_in, const int* in_sizes, int n_in,
                              void* d_out, int out_size, void* d_ws, size_t ws_size,
                              hipStream_t stream)
{
    const float* x    = (const float*)d_in[0];
    const float* Wl_s = (const float*)d_in[1];
    const float* Wl_v = (const float*)d_in[2];
    const float* Wl_t = (const float*)d_in[3];
    const float* Wr0  = (const float*)d_in[4];
    const float* Wr1  = (const float*)d_in[5];
    const float* Wr2  = (const float*)d_in[6];
    const float* Wr3  = (const float*)d_in[7];
    const float* Wm_s = (const float*)d_in[8];
    const float* Wm_v = (const float*)d_in[9];
    const float* Wm_t = (const float*)d_in[10];
    const float* Wn_s = (const float*)d_in[11];
    const float* Wn_v = (const float*)d_in[12];
    const float* Wn_t = (const float*)d_in[13];
    const float* Wp_s = (const float*)d_in[14];
    const float* Wp_v = (const float*)d_in[15];
    const float* Wp_t = (const float*)d_in[16];
    const int* snd = (const int*)d_in[17];
    const int* rcv = (const int*)d_in[18];
    float* out = (float*)d_out;

    char* ws = (char*)d_ws;
    size_t off = 0;
    float* cur    = (float*)(ws + off); off += (size_t)NN * FEAT * 4;
    float* agg    = (float*)(ws + off); off += (size_t)NN * 72 * 4;
    float* msg    = (float*)(ws + off); off += (size_t)NE * MSTRIDE * 4;
    int*   counts = (int*)(ws + off);   off += (size_t)NN * 4;
    int*   offs   = (int*)(ws + off);   off += (size_t)(NN + 1) * 4 + 12;
    int*   rank   = (int*)(ws + off);   off += (size_t)NE * 4;
    int*   elist  = (int*)(ws + off);   off += (size_t)NE * 4;
    float* W3t    = (float*)(ws + off); off += (size_t)3 * NIR * DH * 4;
    size_t avail = (ws_size > off) ? (ws_size - off) : 0;
    long long chunkE = (long long)(avail / ((size_t)(DH + DH + NIR) * sizeof(float)));
    chunkE &= ~255LL;
    if (chunkE > NE) chunkE = NE;
    if (chunkE < 4096) chunkE = 4096;
    float* h2buf = (float*)(ws + off);
    float* h3buf = h2buf + (size_t)DH * chunkE;
    float* wbuf  = h3buf + (size_t)DH * chunkE;

    hipMemcpyAsync(cur, x, (size_t)NN * FEAT * 4, hipMemcpyDeviceToDevice, stream);
    hipMemsetAsync(counts, 0, (size_t)NN * 4, stream);
    csr_hist<<<(NE + 255) / 256, 256, 0, stream>>>(rcv, counts, rank);
    csr_scan<<<1, 1024, 0, stream>>>(counts, offs);
    csr_fill<<<(NE + 255) / 256, 256, 0, stream>>>(rcv, offs, rank, elist);
    w3t_kernel<<<(3 * NIR * DH + 255) / 256, 256, 0, stream>>>(Wr3, W3t);

    for (int k = 0; k < 3; k++) {
        const float* W0  = Wr0 + (size_t)k * 4 * DH;
        const float* W1  = Wr1 + (size_t)k * DH * DH;
        const float* W2  = Wr2 + (size_t)k * DH * DH;
        const float* W3tk= W3t + (size_t)k * NIR * DH;
        const float* Wls = Wl_s + (size_t)k * 16 * 16;
        const float* Wlv = Wl_v + (size_t)k * 8 * 8;
        const float* Wlt = Wl_t + (size_t)k * 4 * 4;
        const float* Wms = Wm_s + (size_t)k * SC * 28;
        const float* Wmv = Wm_v + (size_t)k * VC * 8;
        const float* Wmt = Wm_t + (size_t)k * TC * 4;
        const float* Wns = Wn_s + (size_t)k * 16 * 28;
        const float* Wnv = Wn_v + (size_t)k * 8 * 8;
        const float* Wnt = Wn_t + (size_t)k * 4 * 4;
        const float* Wps = Wp_s + (size_t)k * 16 * 16;
        const float* Wpv = Wp_v + (size_t)k * 8 * 8;
        const float* Wpt = Wp_t + (size_t)k * 4 * 4;

        for (long long e0 = 0; e0 < NE; e0 += chunkE) {
            long long e1 = e0 + chunkE; if (e1 > NE) e1 = NE;
            long long n = e1 - e0;
            int nb = (int)((n + 255) / 256);
            r01_kernel<<<2 * nb, 256, 0, stream>>>(cur, snd, rcv, W0, W1,
                                                   h2buf, (int)e0, (int)e1, (int)chunkE, nb);
            r2_kernel<<<2 * nb, 256, 0, stream>>>(W2, h2buf, h3buf, (int)n, (int)chunkE, nb);
            r3_kernel<<<2 * nb, 256, 0, stream>>>(W3tk, h3buf, wbuf, (int)n, (int)chunkE, nb);
            tp3_kernel<<<3 * nb, 256, 0, stream>>>(cur, snd, rcv, Wls, Wlv, Wlt,
                                                   Wms, Wmv, Wmt, wbuf, msg,
                                                   (int)e0, (int)e1, (int)chunkE, nb);
        }
        gather_kernel<<<(NN + 3) / 4, 256, 0, stream>>>(
            (const float4*)msg, offs, elist, (float4*)agg);
        float* dst = (k == 2) ? out : cur;
        node_kernel<<<(NN + 255) / 256, 256, 0, stream>>>(cur, agg, Wns, Wnv, Wnt,
                                                          Wps, Wpv, Wpt, dst);
    }
}